// Round 10
// baseline (158.879 us; speedup 1.0000x reference)
//
#include <hip/hip_runtime.h>
#include <hip/hip_bf16.h>
#include <stdint.h>

namespace gat {
constexpr int NB   = 16;
constexpr int NN   = 512;
constexpr int FIN  = 256;
constexpr int FOUT = 256;
constexpr int H    = 8;
constexpr int NE   = 50;
constexpr float L2E  = 1.4426950408889634f;   // log2(e)
constexpr float MASKB = -192.0f;              // masked emb entry: after leaky*0.2 + exp2 -> ~5e-11
constexpr float RBIAS = 0.00281502f;          // counters bf16-truncation bias
}
using namespace gat;

typedef __attribute__((ext_vector_type(8))) short short8;
typedef __attribute__((ext_vector_type(4))) float f32x4;

__device__ __forceinline__ unsigned pk_bf16(unsigned ulo, unsigned uhi) {
  return __builtin_amdgcn_perm(uhi, ulo, 0x07060302u);   // take high halves (truncate)
}
__device__ __forceinline__ unsigned pk2f(float a, float b) {
  return pk_bf16(__float_as_uint(a) + 0x8000u, __float_as_uint(b) + 0x8000u);
}
__device__ __forceinline__ unsigned short bf1(float a) {
  return (unsigned short)((__float_as_uint(a) + 0x8000u) >> 16);
}

// ---------------- k_prew: W transpose + aug v1/v2 columns (tiny, 257 blocks) ----------------
__global__ __launch_bounds__(256) void k_prew(const float* __restrict__ Wm,
                                              const float* __restrict__ a1,
                                              const float* __restrict__ a2,
                                              unsigned short* __restrict__ WbTa) {
  const int blk = blockIdx.x;
  if (blk < 256) {
    const int k = blk;
    const int f = threadIdx.x;
    WbTa[f * FIN + k] = bf1(Wm[k * FOUT + f]);
  } else {
    const int k = threadIdx.x;
    const float* wr = Wm + (size_t)k * FOUT;
    #pragma unroll
    for (int h = 0; h < H; ++h) {
      float v1 = 0.f, v2 = 0.f;
      #pragma unroll
      for (int d = 0; d < 32; ++d) {
        const float wv = wr[h * 32 + d];
        v1 += wv * a1[d];
        v2 += wv * a2[d];
      }
      WbTa[(256 + h) * FIN + k] = bf1(v1);
      WbTa[(264 + h) * FIN + k] = bf1(v2);
    }
  }
}

// ------- k_gp (fused): blocks 0..511 = GEMM [Wh|s1|s2]; blocks 512..1535 = codes pack -------
__global__ __launch_bounds__(256, 4) void k_gp(
    const float* __restrict__ x, const unsigned short* __restrict__ WbTa,
    const int* __restrict__ adj, const int* __restrict__ ety,
    unsigned short* __restrict__ WhT, float* __restrict__ s1T, float* __restrict__ s2T,
    unsigned* __restrict__ codes)
{
  const int t = threadIdx.x;
  if (blockIdx.x >= 512) {   // ---- pack role ----
    const size_t base = ((size_t)(blockIdx.x - 512) * 256 + t) * 16;
    const int4* ap = (const int4*)(adj + base);
    const int4* ep = (const int4*)(ety + base);
    unsigned o[4];
    #pragma unroll
    for (int g = 0; g < 4; ++g) {
      const int4 a = ap[g];
      const int4 e = ep[g];
      o[g] = (unsigned)(e.x | (a.x << 6))
           | ((unsigned)(e.y | (a.y << 6)) << 8)
           | ((unsigned)(e.z | (a.z << 6)) << 16)
           | ((unsigned)(e.w | (a.w << 6)) << 24);
    }
    uint4 v; v.x = o[0]; v.y = o[1]; v.z = o[2]; v.w = o[3];
    *(uint4*)(codes + base / 4) = v;
    return;
  }

  // ---- GEMM role ----
  __shared__ alignas(16) unsigned short xS[16 * 264];
  const int row0 = blockIdx.x * 16;
  {
    const int r  = t >> 4;
    const int kb = (t & 15) * 16;
    const float4* xg = (const float4*)(x + (size_t)(row0 + r) * FIN + kb);
    const float4 v0 = xg[0], v1 = xg[1], v2 = xg[2], v3 = xg[3];
    uint4 o0, o1;
    o0.x = pk2f(v0.x, v0.y); o0.y = pk2f(v0.z, v0.w);
    o0.z = pk2f(v1.x, v1.y); o0.w = pk2f(v1.z, v1.w);
    o1.x = pk2f(v2.x, v2.y); o1.y = pk2f(v2.z, v2.w);
    o1.z = pk2f(v3.x, v3.y); o1.w = pk2f(v3.z, v3.w);
    *(uint4*)&xS[r * 264 + kb]     = o0;
    *(uint4*)&xS[r * 264 + kb + 8] = o1;
  }
  __syncthreads();

  const int w    = t >> 6;
  const int L    = t & 63;
  const int nn   = L & 15;
  const int quad = L >> 4;
  const unsigned short* wb = WbTa + (size_t)(w * 64 + nn) * FIN + quad * 8;
  const unsigned short* wa = WbTa + (size_t)(256 + nn) * FIN + quad * 8;
  const unsigned short* xp = &xS[nn * 264 + quad * 8];

  f32x4 acc0 = {0.f,0.f,0.f,0.f}, acc1 = {0.f,0.f,0.f,0.f};
  f32x4 acc2 = {0.f,0.f,0.f,0.f}, acc3 = {0.f,0.f,0.f,0.f};
  f32x4 accA = {0.f,0.f,0.f,0.f};

  #pragma unroll
  for (int kc = 0; kc < 8; ++kc) {
    const int k0 = kc * 32;
    const short8 A  = *(const short8*)(xp + k0);
    const short8 B0 = *(const short8*)(wb + k0);
    const short8 B1 = *(const short8*)(wb + 16 * FIN + k0);
    const short8 B2 = *(const short8*)(wb + 32 * FIN + k0);
    const short8 B3 = *(const short8*)(wb + 48 * FIN + k0);
    acc0 = __builtin_amdgcn_mfma_f32_16x16x32_bf16(A, B0, acc0, 0, 0, 0);
    acc1 = __builtin_amdgcn_mfma_f32_16x16x32_bf16(A, B1, acc1, 0, 0, 0);
    acc2 = __builtin_amdgcn_mfma_f32_16x16x32_bf16(A, B2, acc2, 0, 0, 0);
    acc3 = __builtin_amdgcn_mfma_f32_16x16x32_bf16(A, B3, acc3, 0, 0, 0);
    if (w == 3) {
      const short8 BA = *(const short8*)(wa + k0);
      accA = __builtin_amdgcn_mfma_f32_16x16x32_bf16(A, BA, accA, 0, 0, 0);
    }
  }

  const int b     = row0 >> 9;
  const int node0 = (row0 & 511) + quad * 4;
  f32x4 accs[4] = {acc0, acc1, acc2, acc3};
  #pragma unroll
  for (int ft = 0; ft < 4; ++ft) {
    const int f = w * 64 + ft * 16 + nn;
    uint2 o;
    o.x = pk2f(accs[ft][0], accs[ft][1]);
    o.y = pk2f(accs[ft][2], accs[ft][3]);
    *(uint2*)(WhT + (size_t)((b * 8 + (f >> 5)) * 32 + (f & 31)) * 512 + node0) = o;
  }
  if (w == 3) {
    float4 sv;
    sv.x = accA[0] * L2E; sv.y = accA[1] * L2E;
    sv.z = accA[2] * L2E; sv.w = accA[3] * L2E;
    float* dst = (nn < 8) ? (s1T + (size_t)(b * 8 + nn) * 512 + node0)
                          : (s2T + (size_t)(b * 8 + (nn - 8)) * 512 + node0);
    *(float4*)dst = sv;
  }
}

// ---------------- k_attn (j-quarters, 1024 thr, 2x occupancy): e -> MFMA -> softmax -> LN ----
// 512 blocks x 1024 thr (16 waves): wave (w: heads {w,w+4}) x (jq: j-quarter of 128, 4 kc).
// Cross-quarter (acc,l) combine via 2-round pairwise LDS tree. 32 waves/CU (vs r9's 16).
__global__ __launch_bounds__(1024, 8) void k_attn(
    const unsigned char* __restrict__ codes,
    const float* __restrict__ s1T, const float* __restrict__ s2T,
    const unsigned short* __restrict__ WhT, const float* __restrict__ emb,
    const float* __restrict__ gam, const float* __restrict__ bet,
    float* __restrict__ out)
{
  __shared__ float2 embS[4 * 128];   //  4096 B
  __shared__ float2 lnS[16 * 4];     //   512 B
  __shared__ float  s2S[8 * 512];    // 16384 B
  __shared__ float  redS[512 * 18];  // 36864 B  (2 slots x 256 tt x 18)  -> total 57.9 KB

  const int t    = threadIdx.x;
  const int b    = blockIdx.x >> 5;
  const int i0   = (blockIdx.x & 31) * 16;
  const int W    = t >> 6;          // 0..15
  const int w    = W & 3;           // head pair
  const int jq   = W >> 2;          // j-quarter
  const int L    = t & 63;
  const int i    = L & 15;
  const int quad = L >> 4;
  const int h0   = w, h1 = w + 4;

  { // stage s2 (16 KB): one float4 per thread
    ((float4*)s2S)[t] = ((const float4*)(s2T + (size_t)b * 8 * 512))[t];
  }
  if (t < 512) { // masked emb table: 4 w x 128 c
    const int wp = t >> 7, c = t & 127;
    float2 v;
    if (c >= 64 && c < 64 + NE) {
      v.x = emb[(c - 64) * H + wp]     * L2E + RBIAS;
      v.y = emb[(c - 64) * H + wp + 4] * L2E + RBIAS;
    } else {
      v.x = MASKB; v.y = MASKB;
    }
    embS[t] = v;
  }

  const int row   = b * NN + i0 + i;
  const int jbase = jq * 128;
  uint2 cw[4];
  {
    const unsigned char* cp = codes + (size_t)row * NN + jbase + quad * 8;
    #pragma unroll
    for (int kc = 0; kc < 4; ++kc) cw[kc] = *(const uint2*)(cp + kc * 32);
  }
  const float si0 = s1T[(size_t)(b * 8 + h0) * 512 + i0 + i];
  const float si1 = s1T[(size_t)(b * 8 + h1) * 512 + i0 + i];
  const unsigned short* wt00 = WhT + (size_t)((b * 8 + h0) * 32 + i)      * 512;
  const unsigned short* wt01 = WhT + (size_t)((b * 8 + h0) * 32 + 16 + i) * 512;
  const unsigned short* wt10 = WhT + (size_t)((b * 8 + h1) * 32 + i)      * 512;
  const unsigned short* wt11 = WhT + (size_t)((b * 8 + h1) * 32 + 16 + i) * 512;

  f32x4 acc00 = {0.f,0.f,0.f,0.f}, acc01 = {0.f,0.f,0.f,0.f};
  f32x4 acc10 = {0.f,0.f,0.f,0.f}, acc11 = {0.f,0.f,0.f,0.f};
  f32x4 accL0 = {0.f,0.f,0.f,0.f}, accL1 = {0.f,0.f,0.f,0.f};
  const short one_bf = (short)0x3F80;
  const short8 ONES = {one_bf, one_bf, one_bf, one_bf, one_bf, one_bf, one_bf, one_bf};

  const int ja0 = jbase + quad * 8;
  short8 nA00 = *(const short8*)(wt00 + ja0);
  short8 nA01 = *(const short8*)(wt01 + ja0);
  short8 nA10 = *(const short8*)(wt10 + ja0);
  short8 nA11 = *(const short8*)(wt11 + ja0);

  __syncthreads();

  #pragma unroll
  for (int kc = 0; kc < 4; ++kc) {
    const int ja  = jbase + kc * 32 + quad * 8;
    const short8 A00 = nA00, A01 = nA01, A10 = nA10, A11 = nA11;
    {
      const int jn = ja + 32;    // last-iter overread stays inside d_ws
      nA00 = *(const short8*)(wt00 + jn);
      nA01 = *(const short8*)(wt01 + jn);
      nA10 = *(const short8*)(wt10 + jn);
      nA11 = *(const short8*)(wt11 + jn);
    }
    const float4 sa0 = *(const float4*)&s2S[h0 * 512 + ja];
    const float4 sb0 = *(const float4*)&s2S[h0 * 512 + ja + 4];
    const float4 sa1 = *(const float4*)&s2S[h1 * 512 + ja];
    const float4 sb1 = *(const float4*)&s2S[h1 * 512 + ja + 4];
    const float s20[8] = {sa0.x, sa0.y, sa0.z, sa0.w, sb0.x, sb0.y, sb0.z, sb0.w};
    const float s21[8] = {sa1.x, sa1.y, sa1.z, sa1.w, sb1.x, sb1.y, sb1.z, sb1.w};

    unsigned u0[8], u1[8];
    #pragma unroll
    for (int q = 0; q < 8; ++q) {
      const unsigned cword = (q < 4) ? cw[kc].x : cw[kc].y;
      const unsigned c = (cword >> ((q & 3) * 8)) & 0xffu;
      const float2 em = embS[w * 128 + c];
      float e0 = si0 + s20[q] + em.x;
      float e1 = si1 + s21[q] + em.y;
      e0 = fmaxf(e0, 0.2f * e0);
      e1 = fmaxf(e1, 0.2f * e1);
      u0[q] = __float_as_uint(exp2f(e0));
      u1[q] = __float_as_uint(exp2f(e1));
    }
    uint4 U0, U1;
    U0.x = pk_bf16(u0[0], u0[1]); U0.y = pk_bf16(u0[2], u0[3]);
    U0.z = pk_bf16(u0[4], u0[5]); U0.w = pk_bf16(u0[6], u0[7]);
    U1.x = pk_bf16(u1[0], u1[1]); U1.y = pk_bf16(u1[2], u1[3]);
    U1.z = pk_bf16(u1[4], u1[5]); U1.w = pk_bf16(u1[6], u1[7]);
    const short8 B0 = __builtin_bit_cast(short8, U0);
    const short8 B1 = __builtin_bit_cast(short8, U1);

    acc00 = __builtin_amdgcn_mfma_f32_16x16x32_bf16(A00, B0, acc00, 0, 0, 0);
    acc01 = __builtin_amdgcn_mfma_f32_16x16x32_bf16(A01, B0, acc01, 0, 0, 0);
    acc10 = __builtin_amdgcn_mfma_f32_16x16x32_bf16(A10, B1, acc10, 0, 0, 0);
    acc11 = __builtin_amdgcn_mfma_f32_16x16x32_bf16(A11, B1, acc11, 0, 0, 0);
    accL0 = __builtin_amdgcn_mfma_f32_16x16x32_bf16(ONES, B0, accL0, 0, 0, 0);
    accL1 = __builtin_amdgcn_mfma_f32_16x16x32_bf16(ONES, B1, accL1, 0, 0, 0);
  }

  float l0 = accL0[0];   // per-quarter row sum
  float l1 = accL1[0];

  // ---- cross-quarter combine: (0+=1, 2+=3) then (0+=2) ----
  const int tt = (w << 6) | L;   // 0..255
  if (jq & 1) {                  // jq 1 -> slot tt; jq 3 -> slot 256+tt
    float* rp = redS + ((size_t)((jq >> 1) * 256 + tt)) * 18;
    rp[0]=acc00[0]; rp[1]=acc00[1]; rp[2]=acc00[2]; rp[3]=acc00[3];
    rp[4]=acc01[0]; rp[5]=acc01[1]; rp[6]=acc01[2]; rp[7]=acc01[3];
    rp[8]=acc10[0]; rp[9]=acc10[1]; rp[10]=acc10[2]; rp[11]=acc10[3];
    rp[12]=acc11[0]; rp[13]=acc11[1]; rp[14]=acc11[2]; rp[15]=acc11[3];
    rp[16]=l0; rp[17]=l1;
  }
  __syncthreads();
  if (!(jq & 1)) {
    const float* rp = redS + ((size_t)((jq >> 1) * 256 + tt)) * 18;
    acc00[0]+=rp[0]; acc00[1]+=rp[1]; acc00[2]+=rp[2]; acc00[3]+=rp[3];
    acc01[0]+=rp[4]; acc01[1]+=rp[5]; acc01[2]+=rp[6]; acc01[3]+=rp[7];
    acc10[0]+=rp[8]; acc10[1]+=rp[9]; acc10[2]+=rp[10]; acc10[3]+=rp[11];
    acc11[0]+=rp[12]; acc11[1]+=rp[13]; acc11[2]+=rp[14]; acc11[3]+=rp[15];
    l0 += rp[16]; l1 += rp[17];
  }
  __syncthreads();
  if (jq == 2) {
    float* rp = redS + (size_t)tt * 18;
    rp[0]=acc00[0]; rp[1]=acc00[1]; rp[2]=acc00[2]; rp[3]=acc00[3];
    rp[4]=acc01[0]; rp[5]=acc01[1]; rp[6]=acc01[2]; rp[7]=acc01[3];
    rp[8]=acc10[0]; rp[9]=acc10[1]; rp[10]=acc10[2]; rp[11]=acc10[3];
    rp[12]=acc11[0]; rp[13]=acc11[1]; rp[14]=acc11[2]; rp[15]=acc11[3];
    rp[16]=l0; rp[17]=l1;
  }
  __syncthreads();

  float vals[16];
  if (jq == 0) {
    const float* rp = redS + (size_t)tt * 18;
    acc00[0]+=rp[0]; acc00[1]+=rp[1]; acc00[2]+=rp[2]; acc00[3]+=rp[3];
    acc01[0]+=rp[4]; acc01[1]+=rp[5]; acc01[2]+=rp[6]; acc01[3]+=rp[7];
    acc10[0]+=rp[8]; acc10[1]+=rp[9]; acc10[2]+=rp[10]; acc10[3]+=rp[11];
    acc11[0]+=rp[12]; acc11[1]+=rp[13]; acc11[2]+=rp[14]; acc11[3]+=rp[15];
    const float inv0 = __builtin_amdgcn_rcpf(l0 + rp[16]);
    const float inv1 = __builtin_amdgcn_rcpf(l1 + rp[17]);
    #pragma unroll
    for (int r = 0; r < 4; ++r) {
      vals[r]      = acc00[r] * inv0;
      vals[4 + r]  = acc01[r] * inv0;
      vals[8 + r]  = acc10[r] * inv1;
      vals[12 + r] = acc11[r] * inv1;
    }
    float s = 0.f, ss = 0.f;
    #pragma unroll
    for (int k = 0; k < 16; ++k) { s += vals[k]; ss += vals[k] * vals[k]; }
    s += __shfl_xor(s, 16); ss += __shfl_xor(ss, 16);
    s += __shfl_xor(s, 32); ss += __shfl_xor(ss, 32);
    if (quad == 0) { float2 v; v.x = s; v.y = ss; lnS[i * 4 + w] = v; }
  }
  __syncthreads();
  if (jq != 0) return;

  float mu, rstd;
  {
    float S = 0.f, SS = 0.f;
    #pragma unroll
    for (int ww = 0; ww < 4; ++ww) { const float2 v = lnS[i * 4 + ww]; S += v.x; SS += v.y; }
    mu = S * (1.0f / 256.0f);
    const float var = SS * (1.0f / 256.0f) - mu * mu;
    rstd = rsqrtf(var + 1e-5f);
  }
  const int fb[4] = { h0 * 32 + quad * 4, h0 * 32 + 16 + quad * 4,
                      h1 * 32 + quad * 4, h1 * 32 + 16 + quad * 4 };
  #pragma unroll
  for (int g = 0; g < 4; ++g) {
    const float4 gv = *(const float4*)(gam + fb[g]);
    const float4 bv = *(const float4*)(bet + fb[g]);
    float4 o;
    o.x = (vals[g*4+0] - mu) * rstd * gv.x + bv.x;
    o.y = (vals[g*4+1] - mu) * rstd * gv.y + bv.y;
    o.z = (vals[g*4+2] - mu) * rstd * gv.z + bv.z;
    o.w = (vals[g*4+3] - mu) * rstd * gv.w + bv.w;
    o.x = o.x > 0.f ? o.x : exp2f(o.x * L2E) - 1.f;
    o.y = o.y > 0.f ? o.y : exp2f(o.y * L2E) - 1.f;
    o.z = o.z > 0.f ? o.z : exp2f(o.z * L2E) - 1.f;
    o.w = o.w > 0.f ? o.w : exp2f(o.w * L2E) - 1.f;
    *(float4*)(out + (size_t)row * FOUT + fb[g]) = o;
  }
}

extern "C" void kernel_launch(void* const* d_in, const int* in_sizes, int n_in,
                              void* d_out, int out_size, void* d_ws, size_t ws_size,
                              hipStream_t stream) {
  (void)in_sizes; (void)n_in; (void)out_size; (void)ws_size;
  const float* x   = (const float*)d_in[0];
  const int*   adj = (const int*)  d_in[1];
  const int*   ety = (const int*)  d_in[2];
  const float* Wm  = (const float*)d_in[3];
  const float* a1  = (const float*)d_in[4];
  const float* a2  = (const float*)d_in[5];
  const float* emb = (const float*)d_in[6];
  const float* gam = (const float*)d_in[7];
  const float* bet = (const float*)d_in[8];
  float* out = (float*)d_out;

  unsigned short* WhT  = (unsigned short*)d_ws;             // 16*8*32*512 bf16 = 4 MB
  unsigned short* WbTa = WhT + (size_t)NB * H * 32 * 512;   // 272*256 bf16
  float* s1T  = (float*)(WbTa + (size_t)272 * FIN);         // 16*8*512 fp32 (pre-scaled)
  float* s2T  = s1T + (size_t)NB * H * NN;                  // 16*8*512 fp32 (pre-scaled)
  unsigned char* codes = (unsigned char*)(s2T + (size_t)NB * H * NN); // 4.2 MB

  k_prew<<<dim3(257),  dim3(256), 0, stream>>>(Wm, a1, a2, WbTa);
  k_gp  <<<dim3(1536), dim3(256), 0, stream>>>(x, WbTa, adj, ety, WhT, s1T, s2T, (unsigned*)codes);
  k_attn<<<dim3(NB * (NN / 16)), dim3(1024), 0, stream>>>(codes, s1T, s2T, WhT, emb, gam, bet, out);
}

// Round 11
// 135.709 us; speedup vs baseline: 1.1707x; 1.1707x over previous
//
#include <hip/hip_runtime.h>
#include <hip/hip_bf16.h>
#include <stdint.h>

namespace gat {
constexpr int NB   = 16;
constexpr int NN   = 512;
constexpr int FIN  = 256;
constexpr int FOUT = 256;
constexpr int H    = 8;
constexpr int NE   = 50;
constexpr float L2E  = 1.4426950408889634f;   // log2(e)
constexpr float MASKB = -192.0f;              // masked emb entry: exp2 -> ~5e-11
constexpr float RBIAS = 0.00281502f;          // counters bf16-truncation bias
}
using namespace gat;

typedef __attribute__((ext_vector_type(8))) short short8;
typedef __attribute__((ext_vector_type(4))) float f32x4;

__device__ __forceinline__ unsigned pk_bf16(unsigned ulo, unsigned uhi) {
  return __builtin_amdgcn_perm(uhi, ulo, 0x07060302u);   // take high halves (truncate)
}
__device__ __forceinline__ unsigned pk2f(float a, float b) {
  return pk_bf16(__float_as_uint(a) + 0x8000u, __float_as_uint(b) + 0x8000u);
}
__device__ __forceinline__ unsigned short bf1(float a) {
  return (unsigned short)((__float_as_uint(a) + 0x8000u) >> 16);
}

// ---------------- k_prew: W transpose + aug v1/v2 columns (tiny, 257 blocks) ----------------
__global__ __launch_bounds__(256) void k_prew(const float* __restrict__ Wm,
                                              const float* __restrict__ a1,
                                              const float* __restrict__ a2,
                                              unsigned short* __restrict__ WbTa) {
  const int blk = blockIdx.x;
  if (blk < 256) {
    const int k = blk;
    const int f = threadIdx.x;
    WbTa[f * FIN + k] = bf1(Wm[k * FOUT + f]);
  } else {
    const int k = threadIdx.x;
    const float* wr = Wm + (size_t)k * FOUT;
    #pragma unroll
    for (int h = 0; h < H; ++h) {
      float v1 = 0.f, v2 = 0.f;
      #pragma unroll
      for (int d = 0; d < 32; ++d) {
        const float wv = wr[h * 32 + d];
        v1 += wv * a1[d];
        v2 += wv * a2[d];
      }
      WbTa[(256 + h) * FIN + k] = bf1(v1);
      WbTa[(264 + h) * FIN + k] = bf1(v2);
    }
  }
}

// ------- k_gp (fused): blocks 0..511 = GEMM [Wh|s1|s2]; blocks 512..1535 = codes pack -------
__global__ __launch_bounds__(256, 4) void k_gp(
    const float* __restrict__ x, const unsigned short* __restrict__ WbTa,
    const int* __restrict__ adj, const int* __restrict__ ety,
    unsigned short* __restrict__ WhT, float* __restrict__ s1T, float* __restrict__ s2T,
    unsigned* __restrict__ codes)
{
  const int t = threadIdx.x;
  if (blockIdx.x >= 512) {   // ---- pack role ----
    const size_t base = ((size_t)(blockIdx.x - 512) * 256 + t) * 16;
    const int4* ap = (const int4*)(adj + base);
    const int4* ep = (const int4*)(ety + base);
    unsigned o[4];
    #pragma unroll
    for (int g = 0; g < 4; ++g) {
      const int4 a = ap[g];
      const int4 e = ep[g];
      o[g] = (unsigned)(e.x | (a.x << 6))
           | ((unsigned)(e.y | (a.y << 6)) << 8)
           | ((unsigned)(e.z | (a.z << 6)) << 16)
           | ((unsigned)(e.w | (a.w << 6)) << 24);
    }
    uint4 v; v.x = o[0]; v.y = o[1]; v.z = o[2]; v.w = o[3];
    *(uint4*)(codes + base / 4) = v;
    return;
  }

  // ---- GEMM role ----
  __shared__ alignas(16) unsigned short xS[16 * 264];
  const int row0 = blockIdx.x * 16;
  {
    const int r  = t >> 4;
    const int kb = (t & 15) * 16;
    const float4* xg = (const float4*)(x + (size_t)(row0 + r) * FIN + kb);
    const float4 v0 = xg[0], v1 = xg[1], v2 = xg[2], v3 = xg[3];
    uint4 o0, o1;
    o0.x = pk2f(v0.x, v0.y); o0.y = pk2f(v0.z, v0.w);
    o0.z = pk2f(v1.x, v1.y); o0.w = pk2f(v1.z, v1.w);
    o1.x = pk2f(v2.x, v2.y); o1.y = pk2f(v2.z, v2.w);
    o1.z = pk2f(v3.x, v3.y); o1.w = pk2f(v3.z, v3.w);
    *(uint4*)&xS[r * 264 + kb]     = o0;
    *(uint4*)&xS[r * 264 + kb + 8] = o1;
  }
  __syncthreads();

  const int w    = t >> 6;
  const int L    = t & 63;
  const int nn   = L & 15;
  const int quad = L >> 4;
  const unsigned short* wb = WbTa + (size_t)(w * 64 + nn) * FIN + quad * 8;
  const unsigned short* wa = WbTa + (size_t)(256 + nn) * FIN + quad * 8;
  const unsigned short* xp = &xS[nn * 264 + quad * 8];

  f32x4 acc0 = {0.f,0.f,0.f,0.f}, acc1 = {0.f,0.f,0.f,0.f};
  f32x4 acc2 = {0.f,0.f,0.f,0.f}, acc3 = {0.f,0.f,0.f,0.f};
  f32x4 accA = {0.f,0.f,0.f,0.f};

  #pragma unroll
  for (int kc = 0; kc < 8; ++kc) {
    const int k0 = kc * 32;
    const short8 A  = *(const short8*)(xp + k0);
    const short8 B0 = *(const short8*)(wb + k0);
    const short8 B1 = *(const short8*)(wb + 16 * FIN + k0);
    const short8 B2 = *(const short8*)(wb + 32 * FIN + k0);
    const short8 B3 = *(const short8*)(wb + 48 * FIN + k0);
    acc0 = __builtin_amdgcn_mfma_f32_16x16x32_bf16(A, B0, acc0, 0, 0, 0);
    acc1 = __builtin_amdgcn_mfma_f32_16x16x32_bf16(A, B1, acc1, 0, 0, 0);
    acc2 = __builtin_amdgcn_mfma_f32_16x16x32_bf16(A, B2, acc2, 0, 0, 0);
    acc3 = __builtin_amdgcn_mfma_f32_16x16x32_bf16(A, B3, acc3, 0, 0, 0);
    if (w == 3) {
      const short8 BA = *(const short8*)(wa + k0);
      accA = __builtin_amdgcn_mfma_f32_16x16x32_bf16(A, BA, accA, 0, 0, 0);
    }
  }

  const int b     = row0 >> 9;
  const int node0 = (row0 & 511) + quad * 4;
  f32x4 accs[4] = {acc0, acc1, acc2, acc3};
  #pragma unroll
  for (int ft = 0; ft < 4; ++ft) {
    const int f = w * 64 + ft * 16 + nn;
    uint2 o;
    o.x = pk2f(accs[ft][0], accs[ft][1]);
    o.y = pk2f(accs[ft][2], accs[ft][3]);
    *(uint2*)(WhT + (size_t)((b * 8 + (f >> 5)) * 32 + (f & 31)) * 512 + node0) = o;
  }
  if (w == 3) {
    float4 sv;
    sv.x = accA[0] * L2E; sv.y = accA[1] * L2E;
    sv.z = accA[2] * L2E; sv.w = accA[3] * L2E;
    float* dst = (nn < 8) ? (s1T + (size_t)(b * 8 + nn) * 512 + node0)
                          : (s2T + (size_t)(b * 8 + (nn - 8)) * 512 + node0);
    *(float4*)dst = sv;
  }
}

// ---------------- k_attn (r9 frame + e-phase software pipeline) ----------------
// 512 blocks x 512 thr. Wave (w: heads {w,w+4}, jh: j-half). LDS operands (s2 + emb gathers)
// for iteration kc+1 are issued BEFORE the exp/pack/MFMA of kc — moves ~300 cyc of LDS
// latency off the dependence chain (A-frags already pipelined the same way).
__global__ __launch_bounds__(512, 4) void k_attn(
    const unsigned char* __restrict__ codes,
    const float* __restrict__ s1T, const float* __restrict__ s2T,
    const unsigned short* __restrict__ WhT, const float* __restrict__ emb,
    const float* __restrict__ gam, const float* __restrict__ bet,
    float* __restrict__ out)
{
  __shared__ float2 embS[4 * 128];
  __shared__ float2 lnS[16 * 4];
  __shared__ float  s2S[8 * 512];
  __shared__ float  redS[256 * 18];

  const int t    = threadIdx.x;
  const int b    = blockIdx.x >> 5;
  const int i0   = (blockIdx.x & 31) * 16;
  const int W    = t >> 6;
  const int w    = W & 3;
  const int jh   = W >> 2;
  const int L    = t & 63;
  const int i    = L & 15;
  const int quad = L >> 4;
  const int h0   = w, h1 = w + 4;

  {
    const float4* sg = (const float4*)(s2T + (size_t)b * 8 * 512);
    float4* ss = (float4*)s2S;
    ss[t]       = sg[t];
    ss[t + 512] = sg[t + 512];
  }
  { // masked emb table: t covers 4 w x 128 c
    const int wp = t >> 7, c = t & 127;
    float2 v;
    if (c >= 64 && c < 64 + NE) {
      v.x = emb[(c - 64) * H + wp]     * L2E + RBIAS;
      v.y = emb[(c - 64) * H + wp + 4] * L2E + RBIAS;
    } else {
      v.x = MASKB; v.y = MASKB;
    }
    embS[t] = v;
  }

  const int row   = b * NN + i0 + i;
  const int jbase = jh * 256;
  uint2 cw[8];
  {
    const unsigned char* cp = codes + (size_t)row * NN + jbase + quad * 8;
    #pragma unroll
    for (int kc = 0; kc < 8; ++kc) cw[kc] = *(const uint2*)(cp + kc * 32);
  }
  const float si0 = s1T[(size_t)(b * 8 + h0) * 512 + i0 + i];
  const float si1 = s1T[(size_t)(b * 8 + h1) * 512 + i0 + i];
  const unsigned short* wt00 = WhT + (size_t)((b * 8 + h0) * 32 + i)      * 512;
  const unsigned short* wt01 = WhT + (size_t)((b * 8 + h0) * 32 + 16 + i) * 512;
  const unsigned short* wt10 = WhT + (size_t)((b * 8 + h1) * 32 + i)      * 512;
  const unsigned short* wt11 = WhT + (size_t)((b * 8 + h1) * 32 + 16 + i) * 512;

  f32x4 acc00 = {0.f,0.f,0.f,0.f}, acc01 = {0.f,0.f,0.f,0.f};
  f32x4 acc10 = {0.f,0.f,0.f,0.f}, acc11 = {0.f,0.f,0.f,0.f};
  f32x4 accL0 = {0.f,0.f,0.f,0.f}, accL1 = {0.f,0.f,0.f,0.f};
  const short one_bf = (short)0x3F80;
  const short8 ONES = {one_bf, one_bf, one_bf, one_bf, one_bf, one_bf, one_bf, one_bf};

  const float2* embW = embS + w * 128;
  const float*  s2p0 = s2S + h0 * 512;
  const float*  s2p1 = s2S + h1 * 512;

  // A-frag pipeline: kc=0
  const int ja0 = jbase + quad * 8;
  short8 nA00 = *(const short8*)(wt00 + ja0);
  short8 nA01 = *(const short8*)(wt01 + ja0);
  short8 nA10 = *(const short8*)(wt10 + ja0);
  short8 nA11 = *(const short8*)(wt11 + ja0);

  __syncthreads();

  // e-operand pipeline: stage kc=0
  float2 em[8]; float4 sa0, sb0, sa1, sb1;
  {
    sa0 = *(const float4*)&s2p0[ja0];
    sb0 = *(const float4*)&s2p0[ja0 + 4];
    sa1 = *(const float4*)&s2p1[ja0];
    sb1 = *(const float4*)&s2p1[ja0 + 4];
    #pragma unroll
    for (int q = 0; q < 8; ++q) {
      const unsigned cword = (q < 4) ? cw[0].x : cw[0].y;
      em[q] = embW[(cword >> ((q & 3) * 8)) & 0xffu];
    }
  }

  #pragma unroll
  for (int kc = 0; kc < 8; ++kc) {
    const int ja = jbase + kc * 32 + quad * 8;
    const short8 A00 = nA00, A01 = nA01, A10 = nA10, A11 = nA11;
    { // prefetch next A-frags (last-iter overread stays inside d_ws)
      const int jn = ja + 32;
      nA00 = *(const short8*)(wt00 + jn);
      nA01 = *(const short8*)(wt01 + jn);
      nA10 = *(const short8*)(wt10 + jn);
      nA11 = *(const short8*)(wt11 + jn);
    }
    // issue next iteration's LDS operands NOW (latency overlapped with this kc's compute)
    float2 emn[8]; float4 na0, nb0, na1, nb1;
    if (kc < 7) {
      const int jx = ja + 32;
      na0 = *(const float4*)&s2p0[jx];
      nb0 = *(const float4*)&s2p0[jx + 4];
      na1 = *(const float4*)&s2p1[jx];
      nb1 = *(const float4*)&s2p1[jx + 4];
      #pragma unroll
      for (int q = 0; q < 8; ++q) {
        const unsigned cword = (q < 4) ? cw[kc + 1].x : cw[kc + 1].y;
        emn[q] = embW[(cword >> ((q & 3) * 8)) & 0xffu];
      }
    }

    const float s20[8] = {sa0.x, sa0.y, sa0.z, sa0.w, sb0.x, sb0.y, sb0.z, sb0.w};
    const float s21[8] = {sa1.x, sa1.y, sa1.z, sa1.w, sb1.x, sb1.y, sb1.z, sb1.w};
    unsigned u0[8], u1[8];
    #pragma unroll
    for (int q = 0; q < 8; ++q) {
      float e0 = si0 + s20[q] + em[q].x;
      float e1 = si1 + s21[q] + em[q].y;
      e0 = fmaxf(e0, 0.2f * e0);
      e1 = fmaxf(e1, 0.2f * e1);
      u0[q] = __float_as_uint(exp2f(e0));
      u1[q] = __float_as_uint(exp2f(e1));
    }
    uint4 U0, U1;
    U0.x = pk_bf16(u0[0], u0[1]); U0.y = pk_bf16(u0[2], u0[3]);
    U0.z = pk_bf16(u0[4], u0[5]); U0.w = pk_bf16(u0[6], u0[7]);
    U1.x = pk_bf16(u1[0], u1[1]); U1.y = pk_bf16(u1[2], u1[3]);
    U1.z = pk_bf16(u1[4], u1[5]); U1.w = pk_bf16(u1[6], u1[7]);
    const short8 B0 = __builtin_bit_cast(short8, U0);
    const short8 B1 = __builtin_bit_cast(short8, U1);

    acc00 = __builtin_amdgcn_mfma_f32_16x16x32_bf16(A00, B0, acc00, 0, 0, 0);
    acc01 = __builtin_amdgcn_mfma_f32_16x16x32_bf16(A01, B0, acc01, 0, 0, 0);
    acc10 = __builtin_amdgcn_mfma_f32_16x16x32_bf16(A10, B1, acc10, 0, 0, 0);
    acc11 = __builtin_amdgcn_mfma_f32_16x16x32_bf16(A11, B1, acc11, 0, 0, 0);
    accL0 = __builtin_amdgcn_mfma_f32_16x16x32_bf16(ONES, B0, accL0, 0, 0, 0);
    accL1 = __builtin_amdgcn_mfma_f32_16x16x32_bf16(ONES, B1, accL1, 0, 0, 0);

    if (kc < 7) {
      sa0 = na0; sb0 = nb0; sa1 = na1; sb1 = nb1;
      #pragma unroll
      for (int q = 0; q < 8; ++q) em[q] = emn[q];
    }
  }

  const float l0 = accL0[0];   // D[m][i] = l_i for every m
  const float l1 = accL1[0];

  const int tt = (w << 6) | L;
  if (jh == 1) {
    float* rp = redS + tt * 18;
    rp[0]=acc00[0]; rp[1]=acc00[1]; rp[2]=acc00[2]; rp[3]=acc00[3];
    rp[4]=acc01[0]; rp[5]=acc01[1]; rp[6]=acc01[2]; rp[7]=acc01[3];
    rp[8]=acc10[0]; rp[9]=acc10[1]; rp[10]=acc10[2]; rp[11]=acc10[3];
    rp[12]=acc11[0]; rp[13]=acc11[1]; rp[14]=acc11[2]; rp[15]=acc11[3];
    rp[16]=l0; rp[17]=l1;
  }
  __syncthreads();

  float vals[16]; float mu, rstd;
  if (jh == 0) {
    const float* rp = redS + tt * 18;
    acc00[0]+=rp[0]; acc00[1]+=rp[1]; acc00[2]+=rp[2]; acc00[3]+=rp[3];
    acc01[0]+=rp[4]; acc01[1]+=rp[5]; acc01[2]+=rp[6]; acc01[3]+=rp[7];
    acc10[0]+=rp[8]; acc10[1]+=rp[9]; acc10[2]+=rp[10]; acc10[3]+=rp[11];
    acc11[0]+=rp[12]; acc11[1]+=rp[13]; acc11[2]+=rp[14]; acc11[3]+=rp[15];
    const float inv0 = __builtin_amdgcn_rcpf(l0 + rp[16]);
    const float inv1 = __builtin_amdgcn_rcpf(l1 + rp[17]);
    #pragma unroll
    for (int r = 0; r < 4; ++r) {
      vals[r]      = acc00[r] * inv0;
      vals[4 + r]  = acc01[r] * inv0;
      vals[8 + r]  = acc10[r] * inv1;
      vals[12 + r] = acc11[r] * inv1;
    }
    float s = 0.f, ss = 0.f;
    #pragma unroll
    for (int k = 0; k < 16; ++k) { s += vals[k]; ss += vals[k] * vals[k]; }
    s += __shfl_xor(s, 16); ss += __shfl_xor(ss, 16);
    s += __shfl_xor(s, 32); ss += __shfl_xor(ss, 32);
    if (quad == 0) { float2 v; v.x = s; v.y = ss; lnS[i * 4 + w] = v; }
  }
  __syncthreads();
  if (jh == 1) return;
  {
    float S = 0.f, SS = 0.f;
    #pragma unroll
    for (int ww = 0; ww < 4; ++ww) { const float2 v = lnS[i * 4 + ww]; S += v.x; SS += v.y; }
    mu = S * (1.0f / 256.0f);
    const float var = SS * (1.0f / 256.0f) - mu * mu;
    rstd = rsqrtf(var + 1e-5f);
  }
  const int fb[4] = { h0 * 32 + quad * 4, h0 * 32 + 16 + quad * 4,
                      h1 * 32 + quad * 4, h1 * 32 + 16 + quad * 4 };
  #pragma unroll
  for (int g = 0; g < 4; ++g) {
    const float4 gv = *(const float4*)(gam + fb[g]);
    const float4 bv = *(const float4*)(bet + fb[g]);
    float4 o;
    o.x = (vals[g*4+0] - mu) * rstd * gv.x + bv.x;
    o.y = (vals[g*4+1] - mu) * rstd * gv.y + bv.y;
    o.z = (vals[g*4+2] - mu) * rstd * gv.z + bv.z;
    o.w = (vals[g*4+3] - mu) * rstd * gv.w + bv.w;
    o.x = o.x > 0.f ? o.x : exp2f(o.x * L2E) - 1.f;
    o.y = o.y > 0.f ? o.y : exp2f(o.y * L2E) - 1.f;
    o.z = o.z > 0.f ? o.z : exp2f(o.z * L2E) - 1.f;
    o.w = o.w > 0.f ? o.w : exp2f(o.w * L2E) - 1.f;
    *(float4*)(out + (size_t)row * FOUT + fb[g]) = o;
  }
}

extern "C" void kernel_launch(void* const* d_in, const int* in_sizes, int n_in,
                              void* d_out, int out_size, void* d_ws, size_t ws_size,
                              hipStream_t stream) {
  (void)in_sizes; (void)n_in; (void)out_size; (void)ws_size;
  const float* x   = (const float*)d_in[0];
  const int*   adj = (const int*)  d_in[1];
  const int*   ety = (const int*)  d_in[2];
  const float* Wm  = (const float*)d_in[3];
  const float* a1  = (const float*)d_in[4];
  const float* a2  = (const float*)d_in[5];
  const float* emb = (const float*)d_in[6];
  const float* gam = (const float*)d_in[7];
  const float* bet = (const float*)d_in[8];
  float* out = (float*)d_out;

  unsigned short* WhT  = (unsigned short*)d_ws;             // 16*8*32*512 bf16 = 4 MB
  unsigned short* WbTa = WhT + (size_t)NB * H * 32 * 512;   // 272*256 bf16
  float* s1T  = (float*)(WbTa + (size_t)272 * FIN);         // 16*8*512 fp32 (pre-scaled)
  float* s2T  = s1T + (size_t)NB * H * NN;                  // 16*8*512 fp32 (pre-scaled)
  unsigned char* codes = (unsigned char*)(s2T + (size_t)NB * H * NN); // 4.2 MB

  k_prew<<<dim3(257),  dim3(256), 0, stream>>>(Wm, a1, a2, WbTa);
  k_gp  <<<dim3(1536), dim3(256), 0, stream>>>(x, WbTa, adj, ety, WhT, s1T, s2T, (unsigned*)codes);
  k_attn<<<dim3(NB * (NN / 16)), dim3(512), 0, stream>>>(codes, s1T, s2T, WhT, emb, gam, bet, out);
}